// Round 4
// baseline (127.225 us; speedup 1.0000x reference)
//
#include <hip/hip_runtime.h>
#include <hip/hip_bf16.h>
#include <math.h>

#define NN 50000
#define NE 1000000
#define FIN 128
#define FOUT 64
#define NEG 0.2f

#define NB   2048     // dst-range buckets
#define DPB  25       // dsts per bucket; 2000*25 = 50000 exact
#define NBUSED 2000
#define TS   4096     // edges per sort tile
#define NT   245      // 244 full tiles + 576-edge tail (576 = 72*8)
#define RCAP 1024     // per-bucket edge capacity (mean 500, sigma 22 -> 23s)
#define TILE_BLKS 245
#define SITER 4       // strip-iterations per GEMM block (8 waves x 4 = 32 strips)
#define GEMM_BLKS 98  // ceil(3125 / 32)

using short8  = __attribute__((ext_vector_type(8))) short;
using floatx4 = __attribute__((ext_vector_type(4))) float;
using floatx2 = __attribute__((ext_vector_type(2))) float;
using intx4   = __attribute__((ext_vector_type(4))) int;

static __device__ __forceinline__ short f2bf(float f) {
    __hip_bfloat16 h = __float2bfloat16(f);
    return *(short*)&h;
}

// Fused front kernel, 512 threads. Blocks [0,TILE_BLKS) = per-tile LDS
// counting-sort into 2048 buckets (coalesced gofs store, tile-major);
// blocks [TILE_BLKS, +GEMM_BLKS) = MFMA gemm, W staged once in LDS per
// block and reused for SITER*8 strips (W frags + a-vec loads hoisted out
// of the strip loop).
// NOTE (r11 lesson): integer LDS atomics only — fp32 LDS atomicAdd is a
// CAS loop on gfx950 and serializes catastrophically.
__global__ __launch_bounds__(512) void k_front(
    const float* __restrict__ x, const float* __restrict__ W,
    const float* __restrict__ a_src, const float* __restrict__ a_dst,
    const int* __restrict__ ei,
    __hip_bfloat16* __restrict__ Whb, float* __restrict__ s_src,
    float* __restrict__ s_dst,
    unsigned* __restrict__ bdata, int* __restrict__ gofs)
{
    __shared__ int shmem_i[8192];      // 32 KB, role-aliased
    __shared__ int wsum[8];

    const int tid  = threadIdx.x;
    const int lane = tid & 63;
    const int wv   = tid >> 6;

    if (blockIdx.x >= TILE_BLKS) {
        // ---------------- GEMM role ----------------
        // D = A(16x128)·B(128x64) via 4 K-steps x 4 N-tiles of
        // mfma_f32_16x16x32_bf16. A[m=lane&15][k=quad*8+j],
        // B[k=quad*8+j][n=lane&15], C: col=lane&15, row=quad*4+reg.
        short* Wbt = (short*)shmem_i;  // [64][128] bf16, chunk-XOR swizzled

        // Stage W once per block: (k,n) -> Wbt[n*128 + ((k>>3)^(n&15))*8 + (k&7)]
        #pragma unroll
        for (int rep = 0; rep < 16; ++rep) {
            const int e = rep * 512 + tid;          // 0..8191, coalesced
            const int k = e >> 6, n = e & 63;       // W[k][n] = W[e]
            Wbt[n * 128 + (((k >> 3) ^ (n & 15)) << 3) + (k & 7)] = f2bf(W[e]);
        }
        __syncthreads();

        const int col  = lane & 15;
        const int quad = lane >> 4;

        // Hoisted: W fragments (one ds_read_b128 each) + attention vectors.
        short8 bfr[4][4];
        #pragma unroll
        for (int kk = 0; kk < 4; ++kk) {
            #pragma unroll
            for (int nt = 0; nt < 4; ++nt) {
                const int n = nt * 16 + col;
                bfr[kk][nt] = *(const short8*)(
                    Wbt + n * 128 + ((((kk << 2) + quad) ^ (n & 15)) << 3));
            }
        }
        const float av0 = a_src[col], av1 = a_src[16 + col];
        const float av2 = a_src[32 + col], av3 = a_src[48 + col];
        const float bv0 = a_dst[col], bv1 = a_dst[16 + col];
        const float bv2 = a_dst[32 + col], bv3 = a_dst[48 + col];

        const int sbase = (blockIdx.x - TILE_BLKS) * (8 * SITER);
        for (int it = 0; it < SITER; ++it) {
            const int strip = sbase + it * 8 + wv;
            if (strip >= NN / 16) break;           // 3125 strips
            const int row0 = strip * 16;

            floatx4 acc[4] = {{0.f,0.f,0.f,0.f},{0.f,0.f,0.f,0.f},
                              {0.f,0.f,0.f,0.f},{0.f,0.f,0.f,0.f}};

            // x rows are read exactly once -> nontemporal keeps L2/LLC
            // for Whb/bdata which the gather kernel re-reads.
            const float* xrow = x + (size_t)(row0 + col) * FIN + quad * 8;
            #pragma unroll
            for (int kk = 0; kk < 4; ++kk) {
                const floatx4 u0 = __builtin_nontemporal_load(
                    (const floatx4*)(xrow + kk * 32));
                const floatx4 u1 = __builtin_nontemporal_load(
                    (const floatx4*)(xrow + kk * 32 + 4));
                short8 af;
                af[0] = f2bf(u0[0]); af[1] = f2bf(u0[1]);
                af[2] = f2bf(u0[2]); af[3] = f2bf(u0[3]);
                af[4] = f2bf(u1[0]); af[5] = f2bf(u1[1]);
                af[6] = f2bf(u1[2]); af[7] = f2bf(u1[3]);
                #pragma unroll
                for (int nt = 0; nt < 4; ++nt)
                    acc[nt] = __builtin_amdgcn_mfma_f32_16x16x32_bf16(
                        af, bfr[kk][nt], acc[nt], 0, 0, 0);
            }

            float ps[4], pd[4];
            #pragma unroll
            for (int reg = 0; reg < 4; ++reg) {
                ps[reg] = acc[0][reg] * av0 + acc[1][reg] * av1
                        + acc[2][reg] * av2 + acc[3][reg] * av3;
                pd[reg] = acc[0][reg] * bv0 + acc[1][reg] * bv1
                        + acc[2][reg] * bv2 + acc[3][reg] * bv3;
            }

            #pragma unroll
            for (int nt = 0; nt < 4; ++nt)
                #pragma unroll
                for (int reg = 0; reg < 4; ++reg)
                    Whb[(size_t)(row0 + quad * 4 + reg) * FOUT + nt * 16 + col] =
                        __float2bfloat16(acc[nt][reg]);

            #pragma unroll
            for (int off = 1; off < 16; off <<= 1) {
                #pragma unroll
                for (int reg = 0; reg < 4; ++reg) {
                    ps[reg] += __shfl_xor(ps[reg], off);
                    pd[reg] += __shfl_xor(pd[reg], off);
                }
            }
            if (col == 0) {
                #pragma unroll
                for (int reg = 0; reg < 4; ++reg) {
                    s_src[row0 + quad * 4 + reg] = ps[reg];
                    s_dst[row0 + quad * 4 + reg] = pd[reg];
                }
            }
        }
        return;
    }

    // ---------------- TILESORT role ----------------
    int* cnt = shmem_i;                 // [NB]
    int* cur = shmem_i + NB;            // [NB]
    unsigned* srt = (unsigned*)(shmem_i + 2 * NB);   // [TS]

    const int tile = blockIdx.x;
    const int base = tile * TS;
    const int tcnt = (NE - base < TS) ? (NE - base) : TS;

    for (int i = tid; i < NB; i += 512) cnt[i] = 0;
    __syncthreads();

    // 8 consecutive edges per thread, vectorized intx4 nontemporal loads.
    // (Within-bucket order changes vs strided assignment — safe: absmax is
    // bf16-quantization-dominated, order-invariant across r0-r2.)
    unsigned pk[8];
    {
        const int i0e = tid * 8;
        if (i0e < tcnt) {              // tcnt is always a multiple of 8
            const int e = base + i0e;
            const intx4 s0 = __builtin_nontemporal_load((const intx4*)(ei + e));
            const intx4 s1 = __builtin_nontemporal_load((const intx4*)(ei + e + 4));
            const intx4 d0 = __builtin_nontemporal_load((const intx4*)(ei + NE + e));
            const intx4 d1 = __builtin_nontemporal_load((const intx4*)(ei + NE + e + 4));
            pk[0] = ((unsigned)s0[0] << 16) | (unsigned)d0[0];
            pk[1] = ((unsigned)s0[1] << 16) | (unsigned)d0[1];
            pk[2] = ((unsigned)s0[2] << 16) | (unsigned)d0[2];
            pk[3] = ((unsigned)s0[3] << 16) | (unsigned)d0[3];
            pk[4] = ((unsigned)s1[0] << 16) | (unsigned)d1[0];
            pk[5] = ((unsigned)s1[1] << 16) | (unsigned)d1[1];
            pk[6] = ((unsigned)s1[2] << 16) | (unsigned)d1[2];
            pk[7] = ((unsigned)s1[3] << 16) | (unsigned)d1[3];
            #pragma unroll
            for (int j = 0; j < 8; ++j)
                atomicAdd(&cnt[(int)(pk[j] & 0xffffu) / DPB], 1);
        } else {
            #pragma unroll
            for (int j = 0; j < 8; ++j) pk[j] = 0xFFFFFFFFu;
        }
    }
    __syncthreads();

    // exclusive scan of cnt[0..2048): 4 bins/thread, wave scans + combine.
    // Offsets stored coalesced, tile-major: gofs[t][b].
    {
        const int i0 = tid * 4;
        const int v0 = cnt[i0], v1 = cnt[i0 + 1];
        const int v2 = cnt[i0 + 2], v3 = cnt[i0 + 3];
        const int s = v0 + v1 + v2 + v3;
        int inc = s;
        #pragma unroll
        for (int off = 1; off < 64; off <<= 1) {
            const int t = __shfl_up(inc, off);
            if (lane >= off) inc += t;
        }
        if (lane == 63) wsum[wv] = inc;
        __syncthreads();
        int wb = 0;
        #pragma unroll
        for (int w = 0; w < 7; ++w) if (w < wv) wb += wsum[w];
        const int excl = wb + inc - s;
        cur[i0]     = excl;
        cur[i0 + 1] = excl + v0;
        cur[i0 + 2] = excl + v0 + v1;
        cur[i0 + 3] = excl + v0 + v1 + v2;
        *(int4*)(gofs + (size_t)tile * NB + i0) =
            make_int4(excl, excl + v0, excl + v0 + v1, excl + v0 + v1 + v2);
    }
    __syncthreads();

    #pragma unroll
    for (int j = 0; j < 8; ++j) {
        if (pk[j] != 0xFFFFFFFFu) {
            const int b = (int)(pk[j] & 0xffffu) / DPB;
            const int pos = atomicAdd(&cur[b], 1);
            srt[pos] = pk[j];
        }
    }
    __syncthreads();

    for (int i = tid; i < tcnt; i += 512)
        bdata[base + i] = srt[i];
}

// Per-bucket gather (25 dsts, ~500 edges). Lane split: quarter q4 = edge
// slot (4 edges in flight), l4 = feature-quad index; each lane loads one
// uint2 (4 bf16 features) so one wave-load covers FOUR Whb rows (512 B).
// 16-edge inner unroll -> 4 independent load pairs in flight (latency-
// bound loop, 2x MLP). Bucket counting fused into the segment-copy pass
// (one fewer pass + barrier). Output row = one coalesced 256B store.
__global__ __launch_bounds__(256) void k_sortgather(
    const int* __restrict__ gofs, const unsigned* __restrict__ bdata,
    const float* __restrict__ s_src, const float* __restrict__ s_dst,
    const __hip_bfloat16* __restrict__ Whb, float* __restrict__ out)
{
    __shared__ unsigned raw[RCAP];     // 4 KB
    __shared__ uint2 pes[RCAP];        // 8 KB  {row byte offset, ev bits}
    __shared__ float sdl[32];
    __shared__ int cnt[32];
    __shared__ int ofs2[33];
    __shared__ int cur[32];
    __shared__ int wsum[4];

    const int b = (blockIdx.x & 7) * 250 + (blockIdx.x >> 3);  // XCD swizzle
    const int tid = threadIdx.x;
    const int lane = tid & 63;
    const int wv = tid >> 6;
    const int d0 = b * DPB;

    if (tid < 32) {
        cnt[tid] = 0;
        sdl[tid] = (tid < DPB) ? s_dst[d0 + tid] : 0.f;
    }

    // tile-segment lengths: adjacent dwords gofs[t][b], gofs[t][b+1]
    // (~245 lines, L2-shared across the 16 buckets per line; adjacent
    // buckets land on the same XCD under the swizzle).
    int c = 0, o = 0;
    if (tid < NT) {
        const int* gp = gofs + (size_t)tid * NB + b;
        o = gp[0];
        c = gp[1] - o;
    }
    int inc = c;
    #pragma unroll
    for (int off = 1; off < 64; off <<= 1) {
        const int t = __shfl_up(inc, off);
        if (lane >= off) inc += t;
    }
    if (lane == 63) wsum[wv] = inc;
    __syncthreads();
    int wb = 0;
    #pragma unroll
    for (int w = 0; w < 3; ++w) if (w < wv) wb += wsum[w];
    const int segbase = wb + inc - c;
    int tot = wsum[0] + wsum[1] + wsum[2] + wsum[3];
    if (tot > RCAP) tot = RCAP;        // defensive (23-sigma headroom)

    // segment copy with fused dst counting (cnt zeroed before barrier #1)
    {
        const unsigned* bsrc = bdata + (size_t)tid * TS + o;
        int lim = RCAP - segbase; if (lim > c) lim = c; if (lim < 0) lim = 0;
        for (int k = 0; k < lim; ++k) {
            const unsigned v = bsrc[k];
            raw[segbase + k] = v;
            atomicAdd(&cnt[(int)(v & 0xffffu) - d0], 1);
        }
    }
    __syncthreads();

    if (tid < 32) {
        const int cc = (tid < DPB) ? cnt[tid] : 0;
        int in2 = cc;
        #pragma unroll
        for (int off = 1; off < 32; off <<= 1) {
            const int t = __shfl_up(in2, off);
            if (tid >= off) in2 += t;
        }
        ofs2[tid + 1] = in2;
        if (tid == 0) ofs2[0] = 0;
        cur[tid] = in2 - cc;
    }
    __syncthreads();

    // LDS scatter into dst order + fused ev compute -> uint2
    // pes.x = src * 128 (byte offset of the Whb row; src*128 < 2^32).
    for (int i = tid; i < tot; i += 256) {
        const unsigned p = raw[i];
        const int j = (int)(p & 0xffffu) - d0;
        const int pos = atomicAdd(&cur[j], 1);
        float v = s_src[p >> 16] + sdl[j];
        v = (v > 0.f) ? v : NEG * v;
        pes[pos] = make_uint2((p & 0xffff0000u) >> 9,
                              __float_as_uint(__expf(v)));
    }
    __syncthreads();

    // gather: wave = dst; q4 = edge slot (4 at a time), l4 = feature quad
    const int q4 = lane >> 4;          // edge slot 0..3
    const int l4 = lane & 15;          // features 4*l4 .. 4*l4+3
    const char* wbase = (const char*)Whb + (l4 << 3);
    for (int j = wv; j < DPB; j += 4) {
        const int d = d0 + j;
        const int beg = ofs2[j];
        const int end = ofs2[j + 1];
        float a0 = 0.f, a1 = 0.f, a2 = 0.f, a3 = 0.f, dacc = 0.f;
        int i = beg;
        #define GBODY(idx)                                                 \
            {                                                              \
                const uint2 q = pes[idx];                                  \
                const float ev = __uint_as_float(q.y);                     \
                const uint2 u = *(const uint2*)(wbase + q.x);              \
                a0 = fmaf(ev, __uint_as_float(u.x << 16), a0);             \
                a1 = fmaf(ev, __uint_as_float(u.x & 0xffff0000u), a1);     \
                a2 = fmaf(ev, __uint_as_float(u.y << 16), a2);             \
                a3 = fmaf(ev, __uint_as_float(u.y & 0xffff0000u), a3);     \
                dacc += ev;                                                \
            }
        for (; i + 16 <= end; i += 16) {
            GBODY(i + q4)
            GBODY(i + 4 + q4)
            GBODY(i + 8 + q4)
            GBODY(i + 12 + q4)
        }
        for (; i + 8 <= end; i += 8) {
            GBODY(i + q4)
            GBODY(i + 4 + q4)
        }
        for (; i + 4 <= end; i += 4)
            GBODY(i + q4)
        if (i < end && q4 < end - i)
            GBODY(i + q4)
        #undef GBODY
        // combine edge slots: {0,1}+{2,3} then pairs
        a0 += __shfl_xor(a0, 16); a1 += __shfl_xor(a1, 16);
        a2 += __shfl_xor(a2, 16); a3 += __shfl_xor(a3, 16);
        dacc += __shfl_xor(dacc, 16);
        a0 += __shfl_xor(a0, 32); a1 += __shfl_xor(a1, 32);
        a2 += __shfl_xor(a2, 32); a3 += __shfl_xor(a3, 32);
        dacc += __shfl_xor(dacc, 32);
        if (lane < 16) {
            const float rd = 1.f / (dacc + 1e-16f);
            float r0 = a0 * rd, r1 = a1 * rd;
            float r2 = a2 * rd, r3 = a3 * rd;
            r0 = (r0 > 0.f) ? r0 : expm1f(r0);
            r1 = (r1 > 0.f) ? r1 : expm1f(r1);
            r2 = (r2 > 0.f) ? r2 : expm1f(r2);
            r3 = (r3 > 0.f) ? r3 : expm1f(r3);
            floatx4 rr; rr[0] = r0; rr[1] = r1; rr[2] = r2; rr[3] = r3;
            __builtin_nontemporal_store(
                rr, (floatx4*)(out + (size_t)d * FOUT) + l4);
        }
    }
}

extern "C" void kernel_launch(void* const* d_in, const int* in_sizes, int n_in,
                              void* d_out, int out_size, void* d_ws, size_t ws_size,
                              hipStream_t stream)
{
    const float* x     = (const float*)d_in[0];
    const int*   ei    = (const int*)d_in[1];   // [2,E]: src = ei[0..E), dst = ei[E..2E)
    const float* W     = (const float*)d_in[2];
    const float* a_src = (const float*)d_in[3];
    const float* a_dst = (const float*)d_in[4];
    float* out = (float*)d_out;

    // Workspace: Whb 6.4 MB | s_src 200 KB | s_dst 200 KB | gofs 2 MB |
    // bdata 4 MB -> ~12.8 MB. No memsets needed.
    float* ws    = (float*)d_ws;
    __hip_bfloat16* Whb = (__hip_bfloat16*)ws;
    float* s_src = ws + (size_t)NN * FOUT / 2;
    float* s_dst = s_src + NN;
    int*   gofs  = (int*)(s_dst + NN);
    unsigned* bdata = (unsigned*)(gofs + (size_t)NT * NB);

    k_front<<<TILE_BLKS + GEMM_BLKS, 512, 0, stream>>>(
        x, W, a_src, a_dst, ei, Whb, s_src, s_dst, bdata, gofs);
    k_sortgather<<<NBUSED, 256, 0, stream>>>(gofs, bdata, s_src, s_dst,
                                             Whb, out);
}

// Round 5
// 116.752 us; speedup vs baseline: 1.0897x; 1.0897x over previous
//
#include <hip/hip_runtime.h>
#include <hip/hip_bf16.h>
#include <math.h>

#define NN 50000
#define NE 1000000
#define FIN 128
#define FOUT 64
#define NEG 0.2f

#define NB   2048     // dst-range buckets
#define DPB  25       // dsts per bucket; 2000*25 = 50000 exact
#define NBUSED 2000
#define TS   4096     // edges per sort tile
#define NT   245      // 244 full tiles + 576-edge tail (576 = 72*8)
#define RCAP 1024     // per-bucket edge capacity (mean 500, sigma 22 -> 23s)
#define TILE_BLKS 245
#define GEMM_BLKS 391 // ceil(3125 strips / 8 waves)

using short8  = __attribute__((ext_vector_type(8))) short;
using floatx4 = __attribute__((ext_vector_type(4))) float;
using floatx2 = __attribute__((ext_vector_type(2))) float;
using intx4   = __attribute__((ext_vector_type(4))) int;

static __device__ __forceinline__ short f2bf(float f) {
    __hip_bfloat16 h = __float2bfloat16(f);
    return *(short*)&h;
}

// Fused front kernel, 512 threads. Blocks [0,TILE_BLKS) = per-tile LDS
// counting-sort into 2048 buckets (coalesced gofs store, tile-major);
// blocks [TILE_BLKS, +GEMM_BLKS) = MFMA gemm with W staged in LDS
// (bf16, transposed [n][k], chunk-XOR swizzled -> one ds_read_b128 per
// fragment). One strip per wave, 391 blocks — full parallelism (r4
// lesson: SITER strip-looping cut TLP 4x and regressed 9us).
// NOTE (r11 lesson): integer LDS atomics only — fp32 LDS atomicAdd is a
// CAS loop on gfx950 and serializes catastrophically.
__global__ __launch_bounds__(512) void k_front(
    const float* __restrict__ x, const float* __restrict__ W,
    const float* __restrict__ a_src, const float* __restrict__ a_dst,
    const int* __restrict__ ei,
    __hip_bfloat16* __restrict__ Whb, float* __restrict__ s_src,
    float* __restrict__ s_dst,
    unsigned* __restrict__ bdata, int* __restrict__ gofs)
{
    __shared__ int shmem_i[8192];      // 32 KB, role-aliased
    __shared__ int wsum[8];

    const int tid  = threadIdx.x;
    const int lane = tid & 63;
    const int wv   = tid >> 6;

    if (blockIdx.x >= TILE_BLKS) {
        // ---------------- GEMM role ----------------
        // D = A(16x128)·B(128x64) via 4 K-steps x 4 N-tiles of
        // mfma_f32_16x16x32_bf16. A[m=lane&15][k=quad*8+j],
        // B[k=quad*8+j][n=lane&15], C: col=lane&15, row=quad*4+reg.
        short* Wbt = (short*)shmem_i;  // [64][128] bf16, chunk-XOR swizzled

        // Stage W once per block: (k,n) -> Wbt[n*128 + ((k>>3)^(n&15))*8 + (k&7)]
        #pragma unroll
        for (int rep = 0; rep < 16; ++rep) {
            const int e = rep * 512 + tid;          // 0..8191, coalesced
            const int k = e >> 6, n = e & 63;       // W[k][n] = W[e]
            Wbt[n * 128 + (((k >> 3) ^ (n & 15)) << 3) + (k & 7)] = f2bf(W[e]);
        }
        __syncthreads();

        const int col  = lane & 15;
        const int quad = lane >> 4;
        const int strip = (blockIdx.x - TILE_BLKS) * 8 + wv;
        if (strip >= NN / 16) return;          // 3125 strips (after barrier)
        const int row0 = strip * 16;

        short8 bfr[4][4];
        #pragma unroll
        for (int kk = 0; kk < 4; ++kk) {
            #pragma unroll
            for (int nt = 0; nt < 4; ++nt) {
                const int n = nt * 16 + col;
                bfr[kk][nt] = *(const short8*)(
                    Wbt + n * 128 + ((((kk << 2) + quad) ^ (n & 15)) << 3));
            }
        }

        floatx4 acc[4] = {{0.f,0.f,0.f,0.f},{0.f,0.f,0.f,0.f},
                          {0.f,0.f,0.f,0.f},{0.f,0.f,0.f,0.f}};

        // x rows are read exactly once -> nontemporal keeps L2/LLC for
        // Whb/bdata which the gather kernel re-reads.
        const float* xrow = x + (size_t)(row0 + col) * FIN + quad * 8;
        #pragma unroll
        for (int kk = 0; kk < 4; ++kk) {
            const floatx4 u0 = __builtin_nontemporal_load(
                (const floatx4*)(xrow + kk * 32));
            const floatx4 u1 = __builtin_nontemporal_load(
                (const floatx4*)(xrow + kk * 32 + 4));
            short8 af;
            af[0] = f2bf(u0[0]); af[1] = f2bf(u0[1]);
            af[2] = f2bf(u0[2]); af[3] = f2bf(u0[3]);
            af[4] = f2bf(u1[0]); af[5] = f2bf(u1[1]);
            af[6] = f2bf(u1[2]); af[7] = f2bf(u1[3]);
            #pragma unroll
            for (int nt = 0; nt < 4; ++nt)
                acc[nt] = __builtin_amdgcn_mfma_f32_16x16x32_bf16(
                    af, bfr[kk][nt], acc[nt], 0, 0, 0);
        }

        const float av0 = a_src[col], av1 = a_src[16 + col];
        const float av2 = a_src[32 + col], av3 = a_src[48 + col];
        const float bv0 = a_dst[col], bv1 = a_dst[16 + col];
        const float bv2 = a_dst[32 + col], bv3 = a_dst[48 + col];

        float ps[4], pd[4];
        #pragma unroll
        for (int reg = 0; reg < 4; ++reg) {
            ps[reg] = acc[0][reg] * av0 + acc[1][reg] * av1
                    + acc[2][reg] * av2 + acc[3][reg] * av3;
            pd[reg] = acc[0][reg] * bv0 + acc[1][reg] * bv1
                    + acc[2][reg] * bv2 + acc[3][reg] * bv3;
        }

        #pragma unroll
        for (int nt = 0; nt < 4; ++nt)
            #pragma unroll
            for (int reg = 0; reg < 4; ++reg)
                Whb[(size_t)(row0 + quad * 4 + reg) * FOUT + nt * 16 + col] =
                    __float2bfloat16(acc[nt][reg]);

        #pragma unroll
        for (int off = 1; off < 16; off <<= 1) {
            #pragma unroll
            for (int reg = 0; reg < 4; ++reg) {
                ps[reg] += __shfl_xor(ps[reg], off);
                pd[reg] += __shfl_xor(pd[reg], off);
            }
        }
        if (col == 0) {
            #pragma unroll
            for (int reg = 0; reg < 4; ++reg) {
                s_src[row0 + quad * 4 + reg] = ps[reg];
                s_dst[row0 + quad * 4 + reg] = pd[reg];
            }
        }
        return;
    }

    // ---------------- TILESORT role ----------------
    int* cnt = shmem_i;                 // [NB]
    int* cur = shmem_i + NB;            // [NB]
    unsigned* srt = (unsigned*)(shmem_i + 2 * NB);   // [TS]

    const int tile = blockIdx.x;
    const int base = tile * TS;
    const int tcnt = (NE - base < TS) ? (NE - base) : TS;

    for (int i = tid; i < NB; i += 512) cnt[i] = 0;
    __syncthreads();

    // 8 consecutive edges per thread, vectorized intx4 nontemporal loads
    // (16 scalar -> 4 vector load instructions; within-bucket order change
    // is safe: absmax is bf16-quantization-dominated, order-invariant
    // across r0-r2).
    unsigned pk[8];
    {
        const int i0e = tid * 8;
        if (i0e < tcnt) {              // tcnt is always a multiple of 8
            const int e = base + i0e;
            const intx4 s0 = __builtin_nontemporal_load((const intx4*)(ei + e));
            const intx4 s1 = __builtin_nontemporal_load((const intx4*)(ei + e + 4));
            const intx4 d0 = __builtin_nontemporal_load((const intx4*)(ei + NE + e));
            const intx4 d1 = __builtin_nontemporal_load((const intx4*)(ei + NE + e + 4));
            pk[0] = ((unsigned)s0[0] << 16) | (unsigned)d0[0];
            pk[1] = ((unsigned)s0[1] << 16) | (unsigned)d0[1];
            pk[2] = ((unsigned)s0[2] << 16) | (unsigned)d0[2];
            pk[3] = ((unsigned)s0[3] << 16) | (unsigned)d0[3];
            pk[4] = ((unsigned)s1[0] << 16) | (unsigned)d1[0];
            pk[5] = ((unsigned)s1[1] << 16) | (unsigned)d1[1];
            pk[6] = ((unsigned)s1[2] << 16) | (unsigned)d1[2];
            pk[7] = ((unsigned)s1[3] << 16) | (unsigned)d1[3];
            #pragma unroll
            for (int j = 0; j < 8; ++j)
                atomicAdd(&cnt[(int)(pk[j] & 0xffffu) / DPB], 1);
        } else {
            #pragma unroll
            for (int j = 0; j < 8; ++j) pk[j] = 0xFFFFFFFFu;
        }
    }
    __syncthreads();

    // exclusive scan of cnt[0..2048): 4 bins/thread, wave scans + combine.
    // Offsets stored coalesced, tile-major: gofs[t][b].
    {
        const int i0 = tid * 4;
        const int v0 = cnt[i0], v1 = cnt[i0 + 1];
        const int v2 = cnt[i0 + 2], v3 = cnt[i0 + 3];
        const int s = v0 + v1 + v2 + v3;
        int inc = s;
        #pragma unroll
        for (int off = 1; off < 64; off <<= 1) {
            const int t = __shfl_up(inc, off);
            if (lane >= off) inc += t;
        }
        if (lane == 63) wsum[wv] = inc;
        __syncthreads();
        int wb = 0;
        #pragma unroll
        for (int w = 0; w < 7; ++w) if (w < wv) wb += wsum[w];
        const int excl = wb + inc - s;
        cur[i0]     = excl;
        cur[i0 + 1] = excl + v0;
        cur[i0 + 2] = excl + v0 + v1;
        cur[i0 + 3] = excl + v0 + v1 + v2;
        *(int4*)(gofs + (size_t)tile * NB + i0) =
            make_int4(excl, excl + v0, excl + v0 + v1, excl + v0 + v1 + v2);
    }
    __syncthreads();

    #pragma unroll
    for (int j = 0; j < 8; ++j) {
        if (pk[j] != 0xFFFFFFFFu) {
            const int b = (int)(pk[j] & 0xffffu) / DPB;
            const int pos = atomicAdd(&cur[b], 1);
            srt[pos] = pk[j];
        }
    }
    __syncthreads();

    for (int i = tid; i < tcnt; i += 512)
        bdata[base + i] = srt[i];
}

// Per-bucket gather (25 dsts, ~500 edges). Lane split: quarter q4 = edge
// slot (4 edges in flight), l4 = feature-quad index; each lane loads one
// uint2 (4 bf16 features) so one wave-load covers FOUR Whb rows (512 B).
// 16-edge inner unroll -> 4 independent load pairs in flight (latency-
// bound loop). Separate parallel count pass (r4 lesson: fusing the count
// atomic into the serial copy loop was a regression suspect). Output row
// = one coalesced 256B store.
__global__ __launch_bounds__(256) void k_sortgather(
    const int* __restrict__ gofs, const unsigned* __restrict__ bdata,
    const float* __restrict__ s_src, const float* __restrict__ s_dst,
    const __hip_bfloat16* __restrict__ Whb, float* __restrict__ out)
{
    __shared__ unsigned raw[RCAP];     // 4 KB
    __shared__ uint2 pes[RCAP];        // 8 KB  {row byte offset, ev bits}
    __shared__ float sdl[32];
    __shared__ int cnt[32];
    __shared__ int ofs2[33];
    __shared__ int cur[32];
    __shared__ int wsum[4];

    const int b = (blockIdx.x & 7) * 250 + (blockIdx.x >> 3);  // XCD swizzle
    const int tid = threadIdx.x;
    const int lane = tid & 63;
    const int wv = tid >> 6;
    const int d0 = b * DPB;

    if (tid < 32) {
        cnt[tid] = 0;
        sdl[tid] = (tid < DPB) ? s_dst[d0 + tid] : 0.f;
    }

    // tile-segment lengths: adjacent dwords gofs[t][b], gofs[t][b+1]
    // (~245 lines, L2-shared across the 16 buckets per line; adjacent
    // buckets land on the same XCD under the swizzle).
    int c = 0, o = 0;
    if (tid < NT) {
        const int* gp = gofs + (size_t)tid * NB + b;
        o = gp[0];
        c = gp[1] - o;
    }
    int inc = c;
    #pragma unroll
    for (int off = 1; off < 64; off <<= 1) {
        const int t = __shfl_up(inc, off);
        if (lane >= off) inc += t;
    }
    if (lane == 63) wsum[wv] = inc;
    __syncthreads();
    int wb = 0;
    #pragma unroll
    for (int w = 0; w < 3; ++w) if (w < wv) wb += wsum[w];
    const int segbase = wb + inc - c;
    int tot = wsum[0] + wsum[1] + wsum[2] + wsum[3];
    if (tot > RCAP) tot = RCAP;        // defensive (23-sigma headroom)

    {
        const unsigned* bsrc = bdata + (size_t)tid * TS + o;
        int lim = RCAP - segbase; if (lim > c) lim = c; if (lim < 0) lim = 0;
        for (int k = 0; k < lim; ++k)
            raw[segbase + k] = bsrc[k];
    }
    __syncthreads();

    for (int i = tid; i < tot; i += 256)
        atomicAdd(&cnt[(int)(raw[i] & 0xffffu) - d0], 1);
    __syncthreads();

    if (tid < 32) {
        const int cc = (tid < DPB) ? cnt[tid] : 0;
        int in2 = cc;
        #pragma unroll
        for (int off = 1; off < 32; off <<= 1) {
            const int t = __shfl_up(in2, off);
            if (tid >= off) in2 += t;
        }
        ofs2[tid + 1] = in2;
        if (tid == 0) ofs2[0] = 0;
        cur[tid] = in2 - cc;
    }
    __syncthreads();

    // LDS scatter into dst order + fused ev compute -> uint2
    // pes.x = src * 128 (byte offset of the Whb row; src*128 < 2^32).
    for (int i = tid; i < tot; i += 256) {
        const unsigned p = raw[i];
        const int j = (int)(p & 0xffffu) - d0;
        const int pos = atomicAdd(&cur[j], 1);
        float v = s_src[p >> 16] + sdl[j];
        v = (v > 0.f) ? v : NEG * v;
        pes[pos] = make_uint2((p & 0xffff0000u) >> 9,
                              __float_as_uint(__expf(v)));
    }
    __syncthreads();

    // gather: wave = dst; q4 = edge slot (4 at a time), l4 = feature quad
    const int q4 = lane >> 4;          // edge slot 0..3
    const int l4 = lane & 15;          // features 4*l4 .. 4*l4+3
    const char* wbase = (const char*)Whb + (l4 << 3);
    for (int j = wv; j < DPB; j += 4) {
        const int d = d0 + j;
        const int beg = ofs2[j];
        const int end = ofs2[j + 1];
        float a0 = 0.f, a1 = 0.f, a2 = 0.f, a3 = 0.f, dacc = 0.f;
        int i = beg;
        #define GBODY(idx)                                                 \
            {                                                              \
                const uint2 q = pes[idx];                                  \
                const float ev = __uint_as_float(q.y);                     \
                const uint2 u = *(const uint2*)(wbase + q.x);              \
                a0 = fmaf(ev, __uint_as_float(u.x << 16), a0);             \
                a1 = fmaf(ev, __uint_as_float(u.x & 0xffff0000u), a1);     \
                a2 = fmaf(ev, __uint_as_float(u.y << 16), a2);             \
                a3 = fmaf(ev, __uint_as_float(u.y & 0xffff0000u), a3);     \
                dacc += ev;                                                \
            }
        for (; i + 16 <= end; i += 16) {
            GBODY(i + q4)
            GBODY(i + 4 + q4)
            GBODY(i + 8 + q4)
            GBODY(i + 12 + q4)
        }
        for (; i + 8 <= end; i += 8) {
            GBODY(i + q4)
            GBODY(i + 4 + q4)
        }
        for (; i + 4 <= end; i += 4)
            GBODY(i + q4)
        if (i < end && q4 < end - i)
            GBODY(i + q4)
        #undef GBODY
        // combine edge slots: {0,1}+{2,3} then pairs
        a0 += __shfl_xor(a0, 16); a1 += __shfl_xor(a1, 16);
        a2 += __shfl_xor(a2, 16); a3 += __shfl_xor(a3, 16);
        dacc += __shfl_xor(dacc, 16);
        a0 += __shfl_xor(a0, 32); a1 += __shfl_xor(a1, 32);
        a2 += __shfl_xor(a2, 32); a3 += __shfl_xor(a3, 32);
        dacc += __shfl_xor(dacc, 32);
        if (lane < 16) {
            const float rd = 1.f / (dacc + 1e-16f);
            float r0 = a0 * rd, r1 = a1 * rd;
            float r2 = a2 * rd, r3 = a3 * rd;
            r0 = (r0 > 0.f) ? r0 : expm1f(r0);
            r1 = (r1 > 0.f) ? r1 : expm1f(r1);
            r2 = (r2 > 0.f) ? r2 : expm1f(r2);
            r3 = (r3 > 0.f) ? r3 : expm1f(r3);
            floatx4 rr; rr[0] = r0; rr[1] = r1; rr[2] = r2; rr[3] = r3;
            __builtin_nontemporal_store(
                rr, (floatx4*)(out + (size_t)d * FOUT) + l4);
        }
    }
}

extern "C" void kernel_launch(void* const* d_in, const int* in_sizes, int n_in,
                              void* d_out, int out_size, void* d_ws, size_t ws_size,
                              hipStream_t stream)
{
    const float* x     = (const float*)d_in[0];
    const int*   ei    = (const int*)d_in[1];   // [2,E]: src = ei[0..E), dst = ei[E..2E)
    const float* W     = (const float*)d_in[2];
    const float* a_src = (const float*)d_in[3];
    const float* a_dst = (const float*)d_in[4];
    float* out = (float*)d_out;

    // Workspace: Whb 6.4 MB | s_src 200 KB | s_dst 200 KB | gofs 2 MB |
    // bdata 4 MB -> ~12.8 MB. No memsets needed.
    float* ws    = (float*)d_ws;
    __hip_bfloat16* Whb = (__hip_bfloat16*)ws;
    float* s_src = ws + (size_t)NN * FOUT / 2;
    float* s_dst = s_src + NN;
    int*   gofs  = (int*)(s_dst + NN);
    unsigned* bdata = (unsigned*)(gofs + (size_t)NT * NB);

    k_front<<<TILE_BLKS + GEMM_BLKS, 512, 0, stream>>>(
        x, W, a_src, a_dst, ei, Whb, s_src, s_dst, bdata, gofs);
    k_sortgather<<<NBUSED, 256, 0, stream>>>(gofs, bdata, s_src, s_dst,
                                             Whb, out);
}